// Round 1
// baseline (160.903 us; speedup 1.0000x reference)
//
#include <hip/hip_runtime.h>

#define B_DIM 8
#define M_MICS 8
#define F_DIM 257
#define T_DIM 2000

// upper-triangular (m<=n) packed index, 36 entries
#define UP(m,n) ((m)*8 - (m)*((m)+1)/2 + (n))
// off-diagonal imag packed index (m<n), 28 entries
#define UPI(m,n) (UP(m,n) - (m) - 1)

// accumulator layout:
// [0..35]   ss_re (upper tri incl diag)
// [36..63]  ss_im (strict upper)
// [64..99]  nn_re
// [100..127] nn_im
// [128] msum_s, [129] msum_n, [130..143] pad (zeros)
#define NACC 144
#define NCHUNK 9

__launch_bounds__(256, 2)
__global__ void mvdr_kernel(const float* __restrict__ sre, const float* __restrict__ sim,
                            const float* __restrict__ smask, const float* __restrict__ nmask,
                            float* __restrict__ out, int out_mode)
{
    const int f = blockIdx.x;
    const int b = blockIdx.y;
    const int tid = threadIdx.x;

    __shared__ float sred[256 * 20];
    __shared__ float spart[16 * 17];
    __shared__ float sPhi[NACC];
    __shared__ float sW[16];

    const size_t mrow = (size_t)F_DIM * T_DIM;                       // per-mic stride
    const size_t base_bf = ((size_t)(b * M_MICS) * F_DIM + f) * T_DIM; // mic 0 row
    const size_t mbase = ((size_t)b * F_DIM + f) * T_DIM;            // mask / out row

    float acc[NACC];
#pragma unroll
    for (int i = 0; i < NACC; ++i) acc[i] = 0.f;

    // ---------------- covariance accumulation (streaming, coalesced) -------------
    for (int g = 0; g < 4; ++g) {
        const int t0 = g * 512 + 2 * tid;
        if (t0 < T_DIM) {
            float yr[M_MICS][2], yi[M_MICS][2];
#pragma unroll
            for (int m = 0; m < M_MICS; ++m) {
                const float2 vr = *reinterpret_cast<const float2*>(sre + base_bf + (size_t)m * mrow + t0);
                const float2 vi = *reinterpret_cast<const float2*>(sim + base_bf + (size_t)m * mrow + t0);
                yr[m][0] = vr.x; yr[m][1] = vr.y;
                yi[m][0] = vi.x; yi[m][1] = vi.y;
            }
            const float2 ms2 = *reinterpret_cast<const float2*>(smask + mbase + t0);
            const float2 mn2 = *reinterpret_cast<const float2*>(nmask + mbase + t0);
            const float msv[2] = { ms2.x, ms2.y };
            const float mnv[2] = { mn2.x, mn2.y };
#pragma unroll
            for (int u = 0; u < 2; ++u) {
                acc[128] += msv[u];
                acc[129] += mnv[u];
#pragma unroll
                for (int m = 0; m < M_MICS; ++m) {
                    const float pd = yr[m][u] * yr[m][u] + yi[m][u] * yi[m][u];
                    acc[UP(m, m)]      += msv[u] * pd;
                    acc[64 + UP(m, m)] += mnv[u] * pd;
#pragma unroll
                    for (int n = m + 1; n < M_MICS; ++n) {
                        const float pr = yr[m][u] * yr[n][u] + yi[m][u] * yi[n][u];
                        const float pi = yi[m][u] * yr[n][u] - yr[m][u] * yi[n][u];
                        acc[UP(m, n)]        += msv[u] * pr;
                        acc[36 + UPI(m, n)]  += msv[u] * pi;
                        acc[64 + UP(m, n)]   += mnv[u] * pr;
                        acc[100 + UPI(m, n)] += mnv[u] * pi;
                    }
                }
            }
        }
    }

    // ---------------- block reduction: acc[144] over 256 threads -> sPhi ---------
#pragma unroll
    for (int c = 0; c < NCHUNK; ++c) {
        float4* dst = reinterpret_cast<float4*>(&sred[tid * 20]);
#pragma unroll
        for (int q = 0; q < 4; ++q) {
            dst[q] = make_float4(acc[c * 16 + q * 4 + 0], acc[c * 16 + q * 4 + 1],
                                 acc[c * 16 + q * 4 + 2], acc[c * 16 + q * 4 + 3]);
        }
        __syncthreads();
        {
            const int col = tid & 15, grp = tid >> 4;
            float v = 0.f;
#pragma unroll
            for (int rr = 0; rr < 16; ++rr) v += sred[(grp * 16 + rr) * 20 + col];
            spart[grp * 17 + col] = v;
        }
        __syncthreads();
        if (tid < 16) {
            float v = 0.f;
#pragma unroll
            for (int gp = 0; gp < 16; ++gp) v += spart[gp * 17 + tid];
            sPhi[c * 16 + tid] = v;
        }
        __syncthreads();
    }

    // ---------------- per-(b,f) solve: wave 0 only, lane = (r,c) ----------------
    if (tid < 64) {
        const int lane = tid;
        const int r = lane >> 3, cc = lane & 7;
        const float Ssum = sPhi[128] + 1e-8f;
        const float Nsum = sPhi[129] + 1e-8f;
        const int mm = (r < cc) ? r : cc;
        const int nn2 = (r < cc) ? cc : r;
        const int P = mm * 8 - mm * (mm + 1) / 2 + nn2;
        const float sgn = (r <= cc) ? 1.f : -1.f;

        const float ssr = sPhi[P] / Ssum;
        const float ssi = (r == cc) ? 0.f : sgn * sPhi[36 + P - mm - 1] / Ssum;
        float ar = sPhi[64 + P] / Nsum + ((r == cc) ? 1e-5f : 0.f);
        float ai = (r == cc) ? 0.f : sgn * sPhi[100 + P - mm - 1] / Nsum;

        // Gauss-Jordan inverse of Phi_nn (Hermitian PD -> no pivoting needed)
        float br = (r == cc) ? 1.f : 0.f, bi = 0.f;
        for (int k = 0; k < 8; ++k) {
            const float pr = __shfl(ar, k * 9, 64);
            const float pi = __shfl(ai, k * 9, 64);
            const float den = pr * pr + pi * pi;
            const float qr = pr / den, qi = -pi / den;
            const bool isk = (r == k);
            const float ar2 = ar * qr - ai * qi;
            const float ai2 = ar * qi + ai * qr;
            const float br2 = br * qr - bi * qi;
            const float bi2 = br * qi + bi * qr;
            ar = isk ? ar2 : ar; ai = isk ? ai2 : ai;
            br = isk ? br2 : br; bi = isk ? bi2 : bi;
            const float rar = __shfl(ar, k * 8 + cc, 64);
            const float rai = __shfl(ai, k * 8 + cc, 64);
            const float rbr = __shfl(br, k * 8 + cc, 64);
            const float rbi = __shfl(bi, k * 8 + cc, 64);
            const float fr = __shfl(ar, r * 8 + k, 64);
            const float fi = __shfl(ai, r * 8 + k, 64);
            const float uar = ar - (fr * rar - fi * rai);
            const float uai = ai - (fr * rai + fi * rar);
            const float ubr = br - (fr * rbr - fi * rbi);
            const float ubi = bi - (fr * rbi + fi * rbr);
            ar = isk ? ar : uar; ai = isk ? ai : uai;
            br = isk ? br : ubr; bi = isk ? bi : ubi;
        }

        // G = Phi_nn_inv @ Phi_ss
        float gr = 0.f, gi = 0.f;
        for (int k = 0; k < 8; ++k) {
            const float ir = __shfl(br, r * 8 + k, 64);
            const float ii = __shfl(bi, r * 8 + k, 64);
            const float skr = __shfl(ssr, k * 8 + cc, 64);
            const float ski = __shfl(ssi, k * 8 + cc, 64);
            gr += ir * skr - ii * ski;
            gi += ir * ski + ii * skr;
        }

        // power iteration (30 iters, matching reference incl. eps)
        float vr = 1.f, vi = 0.f;
        for (int it = 0; it < 30; ++it) {
            float wr2 = gr * vr - gi * vi;
            float wi2 = gr * vi + gi * vr;
            wr2 += __shfl_xor(wr2, 1, 64); wi2 += __shfl_xor(wi2, 1, 64);
            wr2 += __shfl_xor(wr2, 2, 64); wi2 += __shfl_xor(wi2, 2, 64);
            wr2 += __shfl_xor(wr2, 4, 64); wi2 += __shfl_xor(wi2, 4, 64);
            float nrm = wr2 * wr2 + wi2 * wi2;
            nrm += __shfl_xor(nrm, 8, 64);
            nrm += __shfl_xor(nrm, 16, 64);
            nrm += __shfl_xor(nrm, 32, 64);
            const float inv = 1.f / (sqrtf(nrm) + 1e-12f);
            wr2 *= inv; wi2 *= inv;
            vr = __shfl(wr2, cc * 9, 64);
            vi = __shfl(wi2, cc * 9, 64);
        }

        // rtf = v / (v[0] + 1e-8)
        const float v0r = __shfl(vr, 0, 64) + 1e-8f;
        const float v0i = __shfl(vi, 0, 64);
        const float dd = v0r * v0r + v0i * v0i;
        const float rtr = (vr * v0r + vi * v0i) / dd;
        const float rti = (vi * v0r - vr * v0i) / dd;

        // d = Phi_nn_inv @ rtf (row sums)
        float dr = br * rtr - bi * rti;
        float di = br * rti + bi * rtr;
        dr += __shfl_xor(dr, 1, 64); di += __shfl_xor(di, 1, 64);
        dr += __shfl_xor(dr, 2, 64); di += __shfl_xor(di, 2, 64);
        dr += __shfl_xor(dr, 4, 64); di += __shfl_xor(di, 4, 64);

        // denom = Re(rtf^H d) + 1e-8 (diagonal lanes contribute)
        float q = (r == cc) ? (rtr * dr + rti * di) : 0.f;
        q += __shfl_xor(q, 1, 64); q += __shfl_xor(q, 2, 64); q += __shfl_xor(q, 4, 64);
        q += __shfl_xor(q, 8, 64); q += __shfl_xor(q, 16, 64); q += __shfl_xor(q, 32, 64);
        q += 1e-8f;

        if (cc == 0) {
            sW[r]     = dr / q;
            sW[8 + r] = di / q;
        }
    }
    __syncthreads();

    // ---------------- apply pass: enhanced[t] = sum_m conj(w_m) Y[m,t] ----------
    float wr[M_MICS], wi[M_MICS];
#pragma unroll
    for (int m = 0; m < M_MICS; ++m) { wr[m] = sW[m]; wi[m] = sW[8 + m]; }

    for (int g = 0; g < 4; ++g) {
        const int t0 = g * 512 + 2 * tid;
        if (t0 < T_DIM) {
            float er0 = 0.f, ei0 = 0.f, er1 = 0.f, ei1 = 0.f;
#pragma unroll
            for (int m = 0; m < M_MICS; ++m) {
                const float2 vr2 = *reinterpret_cast<const float2*>(sre + base_bf + (size_t)m * mrow + t0);
                const float2 vi2 = *reinterpret_cast<const float2*>(sim + base_bf + (size_t)m * mrow + t0);
                er0 += wr[m] * vr2.x + wi[m] * vi2.x;
                ei0 += wr[m] * vi2.x - wi[m] * vr2.x;
                er1 += wr[m] * vr2.y + wi[m] * vi2.y;
                ei1 += wr[m] * vi2.y - wi[m] * vr2.y;
            }
            if (out_mode == 2) {
                *reinterpret_cast<float4*>(out + 2 * (mbase + t0)) = make_float4(er0, ei0, er1, ei1);
            } else {
                *reinterpret_cast<float2*>(out + mbase + t0) = make_float2(er0, er1);
            }
        }
    }
}

extern "C" void kernel_launch(void* const* d_in, const int* in_sizes, int n_in,
                              void* d_out, int out_size, void* d_ws, size_t ws_size,
                              hipStream_t stream)
{
    const float* sre   = (const float*)d_in[0];
    const float* sim   = (const float*)d_in[1];
    const float* smask = (const float*)d_in[2];
    const float* nmask = (const float*)d_in[3];

    // complex64 output may be exposed as interleaved float32 view (2*B*F*T) or
    // real-cast float32 (B*F*T); branch on out_size.
    const int mode = (out_size >= 2 * B_DIM * F_DIM * T_DIM) ? 2 : 1;

    dim3 grid(F_DIM, B_DIM);
    mvdr_kernel<<<grid, 256, 0, stream>>>(sre, sim, smask, nmask, (float*)d_out, mode);
}